// Round 1
// baseline (759.955 us; speedup 1.0000x reference)
//
#include <hip/hip_runtime.h>
#include <math.h>

// Problem constants
#define BB 128
#define SS 512
#define HH 768
#define NLm1 41        // NL-1
#define LDIM 300
#define PPOS 512       // P
#define NEGC (-1.0e9f)
#define NINF (-1.0e12f)

// Workspace layout (float offsets). Total = 1,544,192 floats ~= 6.2 MB.
#define OFF_KVEC   0          // 2624  (41*64)
#define OFF_WEFF   2624       // 768
#define OFF_C      3392       // 1
#define OFF_SCORES 4096       // 65536 (B*S), scores -> attn in place
#define OFF_POOLED 69632      // 98304 (B*H)
#define OFF_SUBJ   167936     // 98304
#define OFF_OBJ    266240     // 98304
#define OFF_PP     364544     // 393216 (B*4*H) partial pooled
#define OFF_PS     757760     // 393216 partial subj max
#define OFF_PO     1150976    // 393216 partial obj max
// Reuse the partial region after k_reduce consumes it:
#define OFF_CTXA   364544     // 98304
#define OFF_CTXB   462848     // 98304
#define OFF_F1     561152     // 98304
#define OFF_F2     659456     // 38400 (B*300)

__device__ __forceinline__ float gelu_f(float x) {
    return 0.5f * x * (1.0f + erff(x * 0.70710678118654752f));
}
__device__ __forceinline__ float dot4(float4 a, float4 b) {
    return a.x*b.x + a.y*b.y + a.z*b.z + a.w*b.w;
}

// K1a: kvec[l,k] = sum_d label_emb[l+1,d]*WK[l,k,d] + bK[l,k]
__global__ void k_kvec(const float* __restrict__ label_emb, const float* __restrict__ WK,
                       const float* __restrict__ bK, float* __restrict__ ws) {
    int l = blockIdx.x;        // 0..40
    int k = threadIdx.x;       // 0..63
    int idx = l * 64 + k;
    const float4* lab4 = (const float4*)(label_emb + (size_t)(l + 1) * LDIM);
    const float4* wk4  = (const float4*)(WK + (size_t)idx * LDIM);
    float acc = bK[idx];
    #pragma unroll 5
    for (int j = 0; j < 75; ++j) acc += dot4(lab4[j], wk4[j]);
    ws[OFF_KVEC + idx] = acc;
}

// K1b: blocks 0..2 -> w_eff[h] = sum_j kvec[j]*WQ[j,h]; block 3 -> c = sum kvec*bQ
__global__ void k_weff(const float* __restrict__ WQ, const float* __restrict__ bQ,
                       float* __restrict__ ws) {
    __shared__ float kv[2624];
    __shared__ float red[256];
    int t = threadIdx.x;
    for (int i = t; i < 2624; i += 256) kv[i] = ws[OFF_KVEC + i];
    __syncthreads();
    if (blockIdx.x < 3) {
        int h = blockIdx.x * 256 + t;
        float acc = 0.f;
        for (int j = 0; j < 2624; ++j) acc += kv[j] * WQ[(size_t)j * HH + h];
        ws[OFF_WEFF + h] = acc;
    } else {
        float part = 0.f;
        for (int i = t; i < 2624; i += 256) part += kv[i] * bQ[i];
        red[t] = part; __syncthreads();
        for (int s2 = 128; s2 > 0; s2 >>= 1) {
            if (t < s2) red[t] += red[t + s2];
            __syncthreads();
        }
        if (t == 0) ws[OFF_C] = red[0];
    }
}

// K2: scores[row] = (x.w_eff + c)/8 + 41*mask*NEG.  One wave per row, 8 rows/wave.
__global__ __launch_bounds__(256) void k_scores(const float* __restrict__ inputs,
        const int* __restrict__ pos_ids, const int* __restrict__ subj_pos,
        const int* __restrict__ obj_pos, float* __restrict__ ws) {
    int wave = threadIdx.x >> 6, lane = threadIdx.x & 63;
    const float4* in4 = (const float4*)inputs;
    const float4* w4  = (const float4*)(ws + OFF_WEFF);
    float c = ws[OFF_C];
    float4 w0 = w4[lane], w1 = w4[64 + lane], w2 = w4[128 + lane];
    int wid = blockIdx.x * 4 + wave;          // 0..8191
    for (int i = 0; i < 8; ++i) {
        int row = wid + 8192 * i;
        const float4* r4 = in4 + (size_t)row * 192;
        float acc = dot4(r4[lane], w0) + dot4(r4[64 + lane], w1) + dot4(r4[128 + lane], w2);
        #pragma unroll
        for (int off = 32; off > 0; off >>= 1) acc += __shfl_down(acc, off, 64);
        if (lane == 0) {
            bool m = (subj_pos[row] == PPOS) | (obj_pos[row] == PPOS) | (pos_ids[row] == 0);
            float sc = (acc + c) * 0.125f;
            if (m) sc += 41.0f * NEGC;
            ws[OFF_SCORES + row] = sc;
        }
    }
}

// K3: softmax over S per batch row (in place)
__global__ void k_softmax(float* __restrict__ ws) {
    __shared__ float red[256];
    int b = blockIdx.x, t = threadIdx.x;
    float* sc = ws + OFF_SCORES + (size_t)b * SS;
    float v0 = sc[t], v1 = sc[t + 256];
    red[t] = fmaxf(v0, v1); __syncthreads();
    for (int s2 = 128; s2 > 0; s2 >>= 1) {
        if (t < s2) red[t] = fmaxf(red[t], red[t + s2]);
        __syncthreads();
    }
    float m = red[0]; __syncthreads();
    float e0 = expf(v0 - m), e1 = expf(v1 - m);
    red[t] = e0 + e1; __syncthreads();
    for (int s2 = 128; s2 > 0; s2 >>= 1) {
        if (t < s2) red[t] += red[t + s2];
        __syncthreads();
    }
    float inv = 1.0f / red[0];
    sc[t] = e0 * inv; sc[t + 256] = e1 * inv;
}

// K4: partial attn-pool + masked maxes over a 128-s chunk. grid (4, B), block 192 (float4/thread)
__global__ __launch_bounds__(192) void k_pool(const float* __restrict__ inputs,
        const int* __restrict__ subj_pos, const int* __restrict__ obj_pos,
        float* __restrict__ ws) {
    __shared__ float la[128];
    __shared__ int lsf[128];
    __shared__ int lof[128];
    int chunk = blockIdx.x, b = blockIdx.y, t = threadIdx.x;
    int s0 = chunk * 128;
    if (t < 128) {
        int gs = b * SS + s0 + t;
        la[t]  = ws[OFF_SCORES + gs];
        lsf[t] = (subj_pos[gs] == PPOS);
        lof[t] = (obj_pos[gs] == PPOS);
    }
    __syncthreads();
    const float4* in4 = (const float4*)inputs;
    float4 pool = make_float4(0.f, 0.f, 0.f, 0.f);
    float4 smax = make_float4(NINF, NINF, NINF, NINF);
    float4 omax = make_float4(NINF, NINF, NINF, NINF);
    for (int s = 0; s < 128; ++s) {
        float4 x = in4[((size_t)(b * SS + s0 + s)) * 192 + t];
        float a = la[s];
        pool.x += a * x.x; pool.y += a * x.y; pool.z += a * x.z; pool.w += a * x.w;
        if (lsf[s]) {
            smax.x = fmaxf(smax.x, x.x); smax.y = fmaxf(smax.y, x.y);
            smax.z = fmaxf(smax.z, x.z); smax.w = fmaxf(smax.w, x.w);
        }
        if (lof[s]) {
            omax.x = fmaxf(omax.x, x.x); omax.y = fmaxf(omax.y, x.y);
            omax.z = fmaxf(omax.z, x.z); omax.w = fmaxf(omax.w, x.w);
        }
    }
    size_t o = (size_t)(b * 4 + chunk) * 192 + t;
    ((float4*)(ws + OFF_PP))[o] = pool;
    ((float4*)(ws + OFF_PS))[o] = smax;
    ((float4*)(ws + OFF_PO))[o] = omax;
}

// K5: reduce the 4 chunk partials -> pooled / subj_out / obj_out
__global__ void k_reduce(float* __restrict__ ws) {
    int i = blockIdx.x * 256 + threadIdx.x;   // 0..98303
    int b = i / HH, h = i - b * HH;
    float p = 0.f, sm = NINF, om = NINF;
    for (int j = 0; j < 4; ++j) {
        int o = (b * 4 + j) * HH + h;
        p += ws[OFF_PP + o];
        sm = fmaxf(sm, ws[OFF_PS + o]);
        om = fmaxf(om, ws[OFF_PO + o]);
    }
    ws[OFF_POOLED + i] = p;
    ws[OFF_SUBJ + i] = sm;
    ws[OFF_OBJ + i] = om;
}

// K6: ctx_a = pooled @ WV_w.T + WV_b    (grid 384: b = /3, d-chunk = %3)
__global__ void k_ctxa(const float* __restrict__ WV_w, const float* __restrict__ WV_b,
                       float* __restrict__ ws) {
    __shared__ __align__(16) float xr[768];
    int b = blockIdx.x / 3, d0 = (blockIdx.x % 3) * 256, t = threadIdx.x;
    xr[t]       = ws[OFF_POOLED + b * HH + t];
    xr[t + 256] = ws[OFF_POOLED + b * HH + t + 256];
    xr[t + 512] = ws[OFF_POOLED + b * HH + t + 512];
    __syncthreads();
    int d = d0 + t;
    const float4* w4 = (const float4*)(WV_w + (size_t)d * HH);
    const float4* x4 = (const float4*)xr;
    float acc = WV_b[d];
    for (int j = 0; j < 192; ++j) acc += dot4(w4[j], x4[j]);
    ws[OFF_CTXA + b * HH + d] = acc;
}

// K7: ctx_b = gelu(ctx_a @ Wout_w.T + Wout_b)
__global__ void k_ctxb(const float* __restrict__ Wout_w, const float* __restrict__ Wout_b,
                       float* __restrict__ ws) {
    __shared__ __align__(16) float xr[768];
    int b = blockIdx.x / 3, d0 = (blockIdx.x % 3) * 256, t = threadIdx.x;
    xr[t]       = ws[OFF_CTXA + b * HH + t];
    xr[t + 256] = ws[OFF_CTXA + b * HH + t + 256];
    xr[t + 512] = ws[OFF_CTXA + b * HH + t + 512];
    __syncthreads();
    int d = d0 + t;
    const float4* w4 = (const float4*)(Wout_w + (size_t)d * HH);
    const float4* x4 = (const float4*)xr;
    float acc = Wout_b[d];
    for (int j = 0; j < 192; ++j) acc += dot4(w4[j], x4[j]);
    ws[OFF_CTXB + b * HH + d] = gelu_f(acc);
}

// K8: layernorm -> ctx output (d_out offset 5376)
__global__ void k_ln(const float* __restrict__ ln_g, const float* __restrict__ ln_b,
                     float* __restrict__ ws, float* __restrict__ out) {
    __shared__ float red[256];
    __shared__ float red2[256];
    int b = blockIdx.x, t = threadIdx.x;
    const float* x = ws + OFF_CTXB + (size_t)b * HH;
    float a0 = x[t], a1 = x[t + 256], a2 = x[t + 512];
    red[t]  = a0 + a1 + a2;
    red2[t] = a0 * a0 + a1 * a1 + a2 * a2;
    __syncthreads();
    for (int s2 = 128; s2 > 0; s2 >>= 1) {
        if (t < s2) { red[t] += red[t + s2]; red2[t] += red2[t + s2]; }
        __syncthreads();
    }
    float mu  = red[0] * (1.0f / 768.0f);
    float var = red2[0] * (1.0f / 768.0f) - mu * mu;
    float inv = rsqrtf(var + 1e-5f);
    float* o = out + 5376 + (size_t)b * HH;
    o[t]       = (a0 - mu) * inv * ln_g[t]       + ln_b[t];
    o[t + 256] = (a1 - mu) * inv * ln_g[t + 256] + ln_b[t + 256];
    o[t + 512] = (a2 - mu) * inv * ln_g[t + 512] + ln_b[t + 512];
}

// K9: feats1 = gelu([subj,obj,ctx] @ feat_w.T + feat_b)   (grid 384)
__global__ void k_feat1(const float* __restrict__ feat_w, const float* __restrict__ feat_b,
                        const float* __restrict__ out, float* __restrict__ ws) {
    __shared__ __align__(16) float cat[2304];
    int b = blockIdx.x / 3, j0 = (blockIdx.x % 3) * 256, t = threadIdx.x;
    for (int i = t; i < 768; i += 256) {
        cat[i]        = ws[OFF_SUBJ + b * HH + i];
        cat[768 + i]  = ws[OFF_OBJ + b * HH + i];
        cat[1536 + i] = out[5376 + (size_t)b * HH + i];
    }
    __syncthreads();
    int j = j0 + t;
    const float4* w4 = (const float4*)(feat_w + (size_t)j * 2304);
    const float4* c4 = (const float4*)cat;
    float acc = feat_b[j];
    for (int q = 0; q < 576; ++q) acc += dot4(w4[q], c4[q]);
    ws[OFF_F1 + b * HH + j] = gelu_f(acc);
}

// K10: feats2 = gelu(feats1 @ out_w.T + out_b)   (grid B, block 320, j<300)
__global__ void k_feat2(const float* __restrict__ out_w, const float* __restrict__ out_b,
                        float* __restrict__ ws) {
    __shared__ __align__(16) float xr[768];
    int b = blockIdx.x, t = threadIdx.x;
    for (int i = t; i < 768; i += 320) xr[i] = ws[OFF_F1 + b * HH + i];
    __syncthreads();
    if (t < 300) {
        const float4* w4 = (const float4*)(out_w + (size_t)t * HH);
        const float4* x4 = (const float4*)xr;
        float acc = out_b[t];
        for (int q = 0; q < 192; ++q) acc += dot4(w4[q], x4[q]);
        ws[OFF_F2 + b * LDIM + t] = gelu_f(acc);
    }
}

// K11: logits = feats2 @ label_emb.T   (grid B, block 64, l<42)
__global__ void k_logits(const float* __restrict__ label_emb, float* __restrict__ ws,
                         float* __restrict__ out) {
    __shared__ __align__(16) float xr[300];
    int b = blockIdx.x, t = threadIdx.x;
    for (int i = t; i < 300; i += 64) xr[i] = ws[OFF_F2 + b * LDIM + i];
    __syncthreads();
    if (t < 42) {
        const float4* l4 = (const float4*)(label_emb + (size_t)t * LDIM);
        const float4* x4 = (const float4*)xr;
        float acc = 0.f;
        for (int q = 0; q < 75; ++q) acc += dot4(l4[q], x4[q]);
        out[b * 42 + t] = acc;
    }
}

extern "C" void kernel_launch(void* const* d_in, const int* in_sizes, int n_in,
                              void* d_out, int out_size, void* d_ws, size_t ws_size,
                              hipStream_t stream) {
    const float* inputs    = (const float*)d_in[0];
    const int*   pos_ids   = (const int*)d_in[1];
    // d_in[2] dep_ids unused, d_in[5] adj unused
    const int*   subj_pos  = (const int*)d_in[3];
    const int*   obj_pos   = (const int*)d_in[4];
    const float* WQ        = (const float*)d_in[6];
    const float* bQ        = (const float*)d_in[7];
    const float* WK        = (const float*)d_in[8];
    const float* bK        = (const float*)d_in[9];
    const float* WV_w      = (const float*)d_in[10];
    const float* WV_b      = (const float*)d_in[11];
    const float* Wout_w    = (const float*)d_in[12];
    const float* Wout_b    = (const float*)d_in[13];
    const float* ln_g      = (const float*)d_in[14];
    const float* ln_b      = (const float*)d_in[15];
    const float* label_emb = (const float*)d_in[16];
    const float* feat_w    = (const float*)d_in[17];
    const float* feat_b    = (const float*)d_in[18];
    const float* out_w     = (const float*)d_in[19];
    const float* out_b     = (const float*)d_in[20];
    float* out = (float*)d_out;
    float* ws  = (float*)d_ws;

    k_kvec   <<<41, 64, 0, stream>>>(label_emb, WK, bK, ws);
    k_weff   <<<4, 256, 0, stream>>>(WQ, bQ, ws);
    k_scores <<<2048, 256, 0, stream>>>(inputs, pos_ids, subj_pos, obj_pos, ws);
    k_softmax<<<BB, 256, 0, stream>>>(ws);
    k_pool   <<<dim3(4, BB), 192, 0, stream>>>(inputs, subj_pos, obj_pos, ws);
    k_reduce <<<384, 256, 0, stream>>>(ws);
    k_ctxa   <<<384, 256, 0, stream>>>(WV_w, WV_b, ws);
    k_ctxb   <<<384, 256, 0, stream>>>(Wout_w, Wout_b, ws);
    k_ln     <<<BB, 256, 0, stream>>>(ln_g, ln_b, ws, out);
    k_feat1  <<<384, 256, 0, stream>>>(feat_w, feat_b, out, ws);
    k_feat2  <<<BB, 320, 0, stream>>>(out_w, out_b, ws);
    k_logits <<<BB, 64, 0, stream>>>(label_emb, ws, out);
}

// Round 2
// 540.019 us; speedup vs baseline: 1.4073x; 1.4073x over previous
//
#include <hip/hip_runtime.h>
#include <math.h>

// Problem constants
#define BB 128
#define SS 512
#define HH 768
#define PPOS 512       // P
#define NEGC (-1.0e9f)
#define NINF (-1.0e12f)

// Workspace layout (float offsets). Regions are time-multiplexed:
// phase 1 (kvec/weff/scores/pool): KVEC/WEFF/C/SCORES + PP/PS/PO partials
// phase 2 (reduce onward): CAT overlays the dead KVEC..SCORES region,
//                          CTXA..F2 overlay the dead PP region.
#define OFF_KVEC   0          // 2624  (41*64)
#define OFF_WEFF   2624       // 768
#define OFF_C      3392       // 1
#define OFF_SCORES 4096       // 65536 (B*S), scores -> attn in place
#define OFF_CAT    0          // 294912 (B*2304) [subj|obj|ctx], valid after k_pool
#define OFF_POOLED 294912     // 98304 (B*H)
#define OFF_PP     393216     // 393216 (B*4*H) partial pooled
#define OFF_PS     786432     // 393216 partial subj max
#define OFF_PO     1179648    // 393216 partial obj max  (end 1572864 floats ~6.3MB)
#define OFF_CTXA   393216     // 98304 (overlays PP after k_reduce)
#define OFF_CTXB   491520     // 98304
#define OFF_F1     589824     // 98304
#define OFF_F2     688128     // 38400 (B*300)

__device__ __forceinline__ float gelu_f(float x) {
    return 0.5f * x * (1.0f + erff(x * 0.70710678118654752f));
}
__device__ __forceinline__ float dot4(float4 a, float4 b) {
    return a.x*b.x + a.y*b.y + a.z*b.z + a.w*b.w;
}

// ---------------------------------------------------------------------------
// Generic wave-tile GEMM: C[M,N] = act(A[M,K] @ W[N,K]^T + bias)
// Each wave computes a 4(m) x 16(n) tile. lane = (n_sub<<2) | k_sub:
// 16 n-groups x 4 k-lanes; k-lanes sweep K in float4 strides of 4.
// Cross-lane reduce is only 2 shuffle steps (xor 1, xor 2).
// K4 = K/4 (float4 count per row), need not be divisible by 4 (loop guard).
// ---------------------------------------------------------------------------
template<int K4, int ACT>
__global__ __launch_bounds__(256) void k_mm(const float* __restrict__ A,
        const float* __restrict__ W, const float* __restrict__ bias,
        float* __restrict__ C, int M, int N) {
    int lane = threadIdx.x & 63;
    int wave = (blockIdx.x * 256 + threadIdx.x) >> 6;
    int ntn = (N + 15) >> 4;
    int m0 = (wave / ntn) << 2;
    if (m0 >= M) return;
    int n0 = ((wave % ntn) << 4) + (lane >> 2);
    int ks = lane & 3;
    bool nvalid = (n0 < N);
    const float4* A4 = (const float4*)A;
    const float4* w_row = (const float4*)W + (size_t)(nvalid ? n0 : 0) * K4;
    const float4* a0 = A4 + (size_t)m0 * K4;
    const float4* a1 = a0 + K4;
    const float4* a2 = a1 + K4;
    const float4* a3 = a2 + K4;
    float acc0 = 0.f, acc1 = 0.f, acc2 = 0.f, acc3 = 0.f;
    #pragma unroll 4
    for (int j = ks; j < K4; j += 4) {
        float4 wv = w_row[j];
        acc0 += dot4(a0[j], wv);
        acc1 += dot4(a1[j], wv);
        acc2 += dot4(a2[j], wv);
        acc3 += dot4(a3[j], wv);
    }
    acc0 += __shfl_xor(acc0, 1, 64); acc0 += __shfl_xor(acc0, 2, 64);
    acc1 += __shfl_xor(acc1, 1, 64); acc1 += __shfl_xor(acc1, 2, 64);
    acc2 += __shfl_xor(acc2, 1, 64); acc2 += __shfl_xor(acc2, 2, 64);
    acc3 += __shfl_xor(acc3, 1, 64); acc3 += __shfl_xor(acc3, 2, 64);
    if (ks == 0 && nvalid) {
        float b = bias ? bias[n0] : 0.f;
        float v0 = acc0 + b, v1 = acc1 + b, v2 = acc2 + b, v3 = acc3 + b;
        if (ACT == 1) { v0 = gelu_f(v0); v1 = gelu_f(v1); v2 = gelu_f(v2); v3 = gelu_f(v3); }
        C[(size_t)m0 * N + n0] = v0;
        C[(size_t)(m0 + 1) * N + n0] = v1;
        C[(size_t)(m0 + 2) * N + n0] = v2;
        C[(size_t)(m0 + 3) * N + n0] = v3;
    }
}

// K1a: kvec[l,k] = sum_d label_emb[l+1,d]*WK[l,k,d] + bK[l,k].  One wave/output.
// Blocks 0..3 additionally zero-init WEFF (768) and C for k_weff2's atomics.
__global__ __launch_bounds__(256) void k_kvec2(const float* __restrict__ label_emb,
        const float* __restrict__ WK, const float* __restrict__ bK,
        float* __restrict__ ws) {
    if (blockIdx.x < 3) ws[OFF_WEFF + blockIdx.x * 256 + threadIdx.x] = 0.f;
    if (blockIdx.x == 3 && threadIdx.x == 0) ws[OFF_C] = 0.f;
    int lane = threadIdx.x & 63;
    int idx = (blockIdx.x * 256 + threadIdx.x) >> 6;   // 0..2623
    int l = idx >> 6;
    const float4* lab4 = (const float4*)(label_emb + (size_t)(l + 1) * 300);
    const float4* wk4  = (const float4*)(WK + (size_t)idx * 300);
    float acc = dot4(lab4[lane], wk4[lane]);           // 75 float4s per row
    if (lane < 11) acc += dot4(lab4[64 + lane], wk4[64 + lane]);
    #pragma unroll
    for (int off = 32; off > 0; off >>= 1) acc += __shfl_xor(acc, off, 64);
    if (lane == 0) ws[OFF_KVEC + idx] = acc + bK[idx];
}

// K1b: w_eff[h] += sum over j-chunk kvec[j]*WQ[j,h] (atomics), + c = kvec.bQ
// waves 0..491: (jc,hg) tiles; wave 492: c.
__global__ __launch_bounds__(256) void k_weff2(const float* __restrict__ WQ,
        const float* __restrict__ bQ, float* __restrict__ ws) {
    int lane = threadIdx.x & 63;
    int w = (blockIdx.x * 256 + threadIdx.x) >> 6;
    if (w < 492) {
        int jc = w / 12, hg = w % 12;
        int h = hg * 64 + lane;
        const float* wq = WQ + (size_t)(jc * 64) * HH + h;
        const float* kv = ws + OFF_KVEC + jc * 64;
        float acc = 0.f;
        #pragma unroll 8
        for (int j = 0; j < 64; ++j) acc += kv[j] * wq[(size_t)j * HH];
        atomicAdd(&ws[OFF_WEFF + h], acc);
    } else if (w == 492) {
        float acc = 0.f;
        for (int j = lane; j < 2624; j += 64) acc += ws[OFF_KVEC + j] * bQ[j];
        #pragma unroll
        for (int off = 32; off > 0; off >>= 1) acc += __shfl_xor(acc, off, 64);
        if (lane == 0) atomicAdd(&ws[OFF_C], acc);
    }
}

// K2: scores[row] = (x.w_eff + c)/8 + 41*mask*NEG.  One wave per row, 8 rows/wave.
__global__ __launch_bounds__(256) void k_scores(const float* __restrict__ inputs,
        const int* __restrict__ pos_ids, const int* __restrict__ subj_pos,
        const int* __restrict__ obj_pos, float* __restrict__ ws) {
    int wave = threadIdx.x >> 6, lane = threadIdx.x & 63;
    const float4* in4 = (const float4*)inputs;
    const float4* w4  = (const float4*)(ws + OFF_WEFF);
    float c = ws[OFF_C];
    float4 w0 = w4[lane], w1 = w4[64 + lane], w2 = w4[128 + lane];
    int wid = blockIdx.x * 4 + wave;          // 0..8191
    for (int i = 0; i < 8; ++i) {
        int row = wid + 8192 * i;
        const float4* r4 = in4 + (size_t)row * 192;
        float acc = dot4(r4[lane], w0) + dot4(r4[64 + lane], w1) + dot4(r4[128 + lane], w2);
        #pragma unroll
        for (int off = 32; off > 0; off >>= 1) acc += __shfl_down(acc, off, 64);
        if (lane == 0) {
            bool m = (subj_pos[row] == PPOS) | (obj_pos[row] == PPOS) | (pos_ids[row] == 0);
            float sc = (acc + c) * 0.125f;
            if (m) sc += 41.0f * NEGC;
            ws[OFF_SCORES + row] = sc;
        }
    }
}

// K3: softmax over S per batch row (in place)
__global__ void k_softmax(float* __restrict__ ws) {
    __shared__ float red[256];
    int b = blockIdx.x, t = threadIdx.x;
    float* sc = ws + OFF_SCORES + (size_t)b * SS;
    float v0 = sc[t], v1 = sc[t + 256];
    red[t] = fmaxf(v0, v1); __syncthreads();
    for (int s2 = 128; s2 > 0; s2 >>= 1) {
        if (t < s2) red[t] = fmaxf(red[t], red[t + s2]);
        __syncthreads();
    }
    float m = red[0]; __syncthreads();
    float e0 = expf(v0 - m), e1 = expf(v1 - m);
    red[t] = e0 + e1; __syncthreads();
    for (int s2 = 128; s2 > 0; s2 >>= 1) {
        if (t < s2) red[t] += red[t + s2];
        __syncthreads();
    }
    float inv = 1.0f / red[0];
    sc[t] = e0 * inv; sc[t + 256] = e1 * inv;
}

// K4: partial attn-pool + masked maxes over a 128-s chunk. grid (4, B), block 192
__global__ __launch_bounds__(192) void k_pool(const float* __restrict__ inputs,
        const int* __restrict__ subj_pos, const int* __restrict__ obj_pos,
        float* __restrict__ ws) {
    __shared__ float la[128];
    __shared__ int lsf[128];
    __shared__ int lof[128];
    int chunk = blockIdx.x, b = blockIdx.y, t = threadIdx.x;
    int s0 = chunk * 128;
    if (t < 128) {
        int gs = b * SS + s0 + t;
        la[t]  = ws[OFF_SCORES + gs];
        lsf[t] = (subj_pos[gs] == PPOS);
        lof[t] = (obj_pos[gs] == PPOS);
    }
    __syncthreads();
    const float4* in4 = (const float4*)inputs;
    float4 pool = make_float4(0.f, 0.f, 0.f, 0.f);
    float4 smax = make_float4(NINF, NINF, NINF, NINF);
    float4 omax = make_float4(NINF, NINF, NINF, NINF);
    for (int s = 0; s < 128; ++s) {
        float4 x = in4[((size_t)(b * SS + s0 + s)) * 192 + t];
        float a = la[s];
        pool.x += a * x.x; pool.y += a * x.y; pool.z += a * x.z; pool.w += a * x.w;
        if (lsf[s]) {
            smax.x = fmaxf(smax.x, x.x); smax.y = fmaxf(smax.y, x.y);
            smax.z = fmaxf(smax.z, x.z); smax.w = fmaxf(smax.w, x.w);
        }
        if (lof[s]) {
            omax.x = fmaxf(omax.x, x.x); omax.y = fmaxf(omax.y, x.y);
            omax.z = fmaxf(omax.z, x.z); omax.w = fmaxf(omax.w, x.w);
        }
    }
    size_t o = (size_t)(b * 4 + chunk) * 192 + t;
    ((float4*)(ws + OFF_PP))[o] = pool;
    ((float4*)(ws + OFF_PS))[o] = smax;
    ((float4*)(ws + OFF_PO))[o] = omax;
}

// K5: reduce chunk partials -> pooled, and subj/obj maxes directly into CAT
__global__ void k_reduce(float* __restrict__ ws) {
    int i = blockIdx.x * 256 + threadIdx.x;   // 0..98303
    int b = i / HH, h = i - b * HH;
    float p = 0.f, sm = NINF, om = NINF;
    for (int j = 0; j < 4; ++j) {
        int o = (b * 4 + j) * HH + h;
        p += ws[OFF_PP + o];
        sm = fmaxf(sm, ws[OFF_PS + o]);
        om = fmaxf(om, ws[OFF_PO + o]);
    }
    ws[OFF_POOLED + i] = p;
    ws[OFF_CAT + (size_t)b * 2304 + h] = sm;
    ws[OFF_CAT + (size_t)b * 2304 + 768 + h] = om;
}

// K8: layernorm -> ctx output (d_out offset 5376) AND cat[:, 1536:2304]
__global__ void k_ln(const float* __restrict__ ln_g, const float* __restrict__ ln_b,
                     float* __restrict__ ws, float* __restrict__ out) {
    __shared__ float red[256];
    __shared__ float red2[256];
    int b = blockIdx.x, t = threadIdx.x;
    const float* x = ws + OFF_CTXB + (size_t)b * HH;
    float a0 = x[t], a1 = x[t + 256], a2 = x[t + 512];
    red[t]  = a0 + a1 + a2;
    red2[t] = a0 * a0 + a1 * a1 + a2 * a2;
    __syncthreads();
    for (int s2 = 128; s2 > 0; s2 >>= 1) {
        if (t < s2) { red[t] += red[t + s2]; red2[t] += red2[t + s2]; }
        __syncthreads();
    }
    float mu  = red[0] * (1.0f / 768.0f);
    float var = red2[0] * (1.0f / 768.0f) - mu * mu;
    float inv = rsqrtf(var + 1e-5f);
    float* o = out + 5376 + (size_t)b * HH;
    float* cc = ws + OFF_CAT + (size_t)b * 2304 + 1536;
    float r0 = (a0 - mu) * inv * ln_g[t]       + ln_b[t];
    float r1 = (a1 - mu) * inv * ln_g[t + 256] + ln_b[t + 256];
    float r2 = (a2 - mu) * inv * ln_g[t + 512] + ln_b[t + 512];
    o[t] = r0; o[t + 256] = r1; o[t + 512] = r2;
    cc[t] = r0; cc[t + 256] = r1; cc[t + 512] = r2;
}

extern "C" void kernel_launch(void* const* d_in, const int* in_sizes, int n_in,
                              void* d_out, int out_size, void* d_ws, size_t ws_size,
                              hipStream_t stream) {
    const float* inputs    = (const float*)d_in[0];
    const int*   pos_ids   = (const int*)d_in[1];
    const int*   subj_pos  = (const int*)d_in[3];
    const int*   obj_pos   = (const int*)d_in[4];
    const float* WQ        = (const float*)d_in[6];
    const float* bQ        = (const float*)d_in[7];
    const float* WK        = (const float*)d_in[8];
    const float* bK        = (const float*)d_in[9];
    const float* WV_w      = (const float*)d_in[10];
    const float* WV_b      = (const float*)d_in[11];
    const float* Wout_w    = (const float*)d_in[12];
    const float* Wout_b    = (const float*)d_in[13];
    const float* ln_g      = (const float*)d_in[14];
    const float* ln_b      = (const float*)d_in[15];
    const float* label_emb = (const float*)d_in[16];
    const float* feat_w    = (const float*)d_in[17];
    const float* feat_b    = (const float*)d_in[18];
    const float* out_w     = (const float*)d_in[19];
    const float* out_b     = (const float*)d_in[20];
    float* out = (float*)d_out;
    float* ws  = (float*)d_ws;

    k_kvec2  <<<656, 256, 0, stream>>>(label_emb, WK, bK, ws);
    k_weff2  <<<124, 256, 0, stream>>>(WQ, bQ, ws);
    k_scores <<<2048, 256, 0, stream>>>(inputs, pos_ids, subj_pos, obj_pos, ws);
    k_softmax<<<BB, 256, 0, stream>>>(ws);
    k_pool   <<<dim3(4, BB), 192, 0, stream>>>(inputs, subj_pos, obj_pos, ws);
    k_reduce <<<384, 256, 0, stream>>>(ws);
    // ctx_a = pooled @ WV_w.T + WV_b          (M=128,N=768,K=768)
    k_mm<192,0><<<384, 256, 0, stream>>>(ws + OFF_POOLED, WV_w, WV_b, ws + OFF_CTXA, BB, HH);
    // ctx_b = gelu(ctx_a @ Wout_w.T + Wout_b) (M=128,N=768,K=768)
    k_mm<192,1><<<384, 256, 0, stream>>>(ws + OFF_CTXA, Wout_w, Wout_b, ws + OFF_CTXB, BB, HH);
    k_ln     <<<BB, 256, 0, stream>>>(ln_g, ln_b, ws, out);
    // feats1 = gelu(cat @ feat_w.T + feat_b)  (M=128,N=768,K=2304)
    k_mm<576,1><<<384, 256, 0, stream>>>(ws + OFF_CAT, feat_w, feat_b, ws + OFF_F1, BB, HH);
    // feats2 = gelu(f1 @ out_w.T + out_b)     (M=128,N=300,K=768)
    k_mm<192,1><<<152, 256, 0, stream>>>(ws + OFF_F1, out_w, out_b, ws + OFF_F2, BB, 300);
    // logits = f2 @ label_emb.T               (M=128,N=42,K=300)
    k_mm<75,0><<<24, 256, 0, stream>>>(ws + OFF_F2, label_emb, nullptr, out, BB, 42);
}

// Round 3
// 476.482 us; speedup vs baseline: 1.5949x; 1.1333x over previous
//
#include <hip/hip_runtime.h>
#include <math.h>

// Problem constants
#define BB 128
#define SS 512
#define HH 768
#define PPOS 512       // P
#define NEGC (-1.0e9f)
#define NINF (-1.0e12f)

// Workspace layout (float offsets). Regions time-multiplexed:
// phase 1 (kvec/weff/scores/pool): KVEC/WEFF/C/SCORES + PP/PS/PO partials
// phase 2 (reduce onward): CAT overlays dead KVEC..SCORES, CTXA..F2 overlay PP.
#define OFF_KVEC   0          // 2624  (41*64)
#define OFF_WEFF   2624       // 768
#define OFF_C      3392       // 1
#define OFF_SCORES 4096       // 65536 (B*S) raw masked scores
#define OFF_CAT    0          // 294912 (B*2304) [subj|obj|ctx], written by k_reduce/k_ln
#define OFF_POOLED 294912     // 98304 (B*H)
#define OFF_PP     393216     // 786432 (B*8*H) partial pooled
#define OFF_PS     1179648    // 786432 partial subj max
#define OFF_PO     1966080    // 786432 partial obj max (end 2752512 floats ~11MB)
#define OFF_CTXA   393216     // 98304 (overlays PP after k_reduce)
#define OFF_CTXB   491520     // 98304
#define OFF_F1     589824     // 98304
#define OFF_F2     688128     // 38400 (B*300)

__device__ __forceinline__ float gelu_f(float x) {
    return 0.5f * x * (1.0f + erff(x * 0.70710678118654752f));
}
__device__ __forceinline__ float dot4(float4 a, float4 b) {
    return a.x*b.x + a.y*b.y + a.z*b.z + a.w*b.w;
}

// ---------------------------------------------------------------------------
// Wave-tile GEMM: C[M,N] = act(A[M,K] @ W[N,K]^T + bias)
// Each wave computes a MT(m) x 16(n) tile. lane = (n_sub<<2) | k_sub:
// 16 n-groups x 4 k-lanes; k-lanes sweep K in float4 strides of 4.
// Cross-lane reduce = 2 shuffle steps. MT=2 doubles wave count vs MT=4
// (latency-bound short-K tail GEMMs want waves, W re-reads hit L2).
// ---------------------------------------------------------------------------
template<int K4, int ACT, int MT>
__global__ __launch_bounds__(256) void k_mm(const float* __restrict__ A,
        const float* __restrict__ W, const float* __restrict__ bias,
        float* __restrict__ C, int M, int N) {
    int lane = threadIdx.x & 63;
    int wave = (blockIdx.x * 256 + threadIdx.x) >> 6;
    int ntn = (N + 15) >> 4;
    int m0 = (wave / ntn) * MT;
    if (m0 >= M) return;
    int n0 = ((wave % ntn) << 4) + (lane >> 2);
    int ks = lane & 3;
    bool nvalid = (n0 < N);
    const float4* A4 = (const float4*)A;
    const float4* w_row = (const float4*)W + (size_t)(nvalid ? n0 : 0) * K4;
    const float4* ar = A4 + (size_t)m0 * K4;
    float acc[MT];
    #pragma unroll
    for (int r = 0; r < MT; ++r) acc[r] = 0.f;
    #pragma unroll 4
    for (int j = ks; j < K4; j += 4) {
        float4 wv = w_row[j];
        #pragma unroll
        for (int r = 0; r < MT; ++r) acc[r] += dot4(ar[(size_t)r * K4 + j], wv);
    }
    #pragma unroll
    for (int r = 0; r < MT; ++r) {
        acc[r] += __shfl_xor(acc[r], 1, 64);
        acc[r] += __shfl_xor(acc[r], 2, 64);
    }
    if (ks == 0 && nvalid) {
        float b = bias ? bias[n0] : 0.f;
        #pragma unroll
        for (int r = 0; r < MT; ++r) {
            float v = acc[r] + b;
            if (ACT == 1) v = gelu_f(v);
            C[(size_t)(m0 + r) * N + n0] = v;
        }
    }
}

// K1a: kvec[l,k] = sum_d label_emb[l+1,d]*WK[l,k,d] + bK[l,k].  One wave/output.
// Blocks 0..3 additionally zero-init WEFF (768) and C for k_weff2's atomics.
__global__ __launch_bounds__(256) void k_kvec2(const float* __restrict__ label_emb,
        const float* __restrict__ WK, const float* __restrict__ bK,
        float* __restrict__ ws) {
    if (blockIdx.x < 3) ws[OFF_WEFF + blockIdx.x * 256 + threadIdx.x] = 0.f;
    if (blockIdx.x == 3 && threadIdx.x == 0) ws[OFF_C] = 0.f;
    int lane = threadIdx.x & 63;
    int idx = (blockIdx.x * 256 + threadIdx.x) >> 6;   // 0..2623
    int l = idx >> 6;
    const float4* lab4 = (const float4*)(label_emb + (size_t)(l + 1) * 300);
    const float4* wk4  = (const float4*)(WK + (size_t)idx * 300);
    float acc = dot4(lab4[lane], wk4[lane]);           // 75 float4s per row
    if (lane < 11) acc += dot4(lab4[64 + lane], wk4[64 + lane]);
    #pragma unroll
    for (int off = 32; off > 0; off >>= 1) acc += __shfl_xor(acc, off, 64);
    if (lane == 0) ws[OFF_KVEC + idx] = acc + bK[idx];
}

// K1b: w_eff[h] += sum over j-chunk kvec[j]*WQ[j,h] (atomics), + c = kvec.bQ
__global__ __launch_bounds__(256) void k_weff2(const float* __restrict__ WQ,
        const float* __restrict__ bQ, float* __restrict__ ws) {
    int lane = threadIdx.x & 63;
    int w = (blockIdx.x * 256 + threadIdx.x) >> 6;
    if (w < 492) {
        int jc = w / 12, hg = w % 12;
        int h = hg * 64 + lane;
        const float* wq = WQ + (size_t)(jc * 64) * HH + h;
        const float* kv = ws + OFF_KVEC + jc * 64;
        float acc = 0.f;
        #pragma unroll 8
        for (int j = 0; j < 64; ++j) acc += kv[j] * wq[(size_t)j * HH];
        atomicAdd(&ws[OFF_WEFF + h], acc);
    } else if (w == 492) {
        float acc = 0.f;
        for (int j = lane; j < 2624; j += 64) acc += ws[OFF_KVEC + j] * bQ[j];
        #pragma unroll
        for (int off = 32; off > 0; off >>= 1) acc += __shfl_xor(acc, off, 64);
        if (lane == 0) atomicAdd(&ws[OFF_C], acc);
    }
}

// K2: raw scores[row] = (x.w_eff + c)/8 + 41*mask*NEG.  One wave/row, 8 rows/wave.
__global__ __launch_bounds__(256) void k_scores(const float* __restrict__ inputs,
        const int* __restrict__ pos_ids, const int* __restrict__ subj_pos,
        const int* __restrict__ obj_pos, float* __restrict__ ws) {
    int wave = threadIdx.x >> 6, lane = threadIdx.x & 63;
    const float4* in4 = (const float4*)inputs;
    const float4* w4  = (const float4*)(ws + OFF_WEFF);
    float c = ws[OFF_C];
    float4 w0 = w4[lane], w1 = w4[64 + lane], w2 = w4[128 + lane];
    int wid = blockIdx.x * 4 + wave;          // 0..8191
    for (int i = 0; i < 8; ++i) {
        int row = wid + 8192 * i;
        const float4* r4 = in4 + (size_t)row * 192;
        float acc = dot4(r4[lane], w0) + dot4(r4[64 + lane], w1) + dot4(r4[128 + lane], w2);
        #pragma unroll
        for (int off = 32; off > 0; off >>= 1) acc += __shfl_down(acc, off, 64);
        if (lane == 0) {
            bool m = (subj_pos[row] == PPOS) | (obj_pos[row] == PPOS) | (pos_ids[row] == 0);
            float sc = (acc + c) * 0.125f;
            if (m) sc += 41.0f * NEGC;
            ws[OFF_SCORES + row] = sc;
        }
    }
}

// K4: softmax (per-block, redundant across the 8 chunks of a batch) +
// partial attn-pool + masked maxes over a 64-s chunk. grid (8, B), block 192.
__global__ __launch_bounds__(192) void k_pool(const float* __restrict__ inputs,
        const int* __restrict__ subj_pos, const int* __restrict__ obj_pos,
        float* __restrict__ ws) {
    __shared__ float red[256];
    __shared__ float al[64];
    __shared__ int lsf[64];
    __shared__ int lof[64];
    int chunk = blockIdx.x, b = blockIdx.y, t = threadIdx.x;
    int s0 = chunk * 64;
    const float* sc = ws + OFF_SCORES + (size_t)b * SS;
    // --- softmax over the full 512 scores of batch b (block-redundant) ---
    float v0 = sc[t], v1 = sc[t + 192], v2 = (t < 128) ? sc[t + 384] : NINF;
    red[t] = fmaxf(fmaxf(v0, v1), v2);
    if (t >= 128) { }   // red[192..255] untouched; guard reduction below
    if (t < 64) red[t + 192] = NINF;
    __syncthreads();
    for (int s2 = 128; s2 > 0; s2 >>= 1) {
        if (t < s2) red[t] = fmaxf(red[t], red[t + s2]);
        __syncthreads();
    }
    float m = red[0];
    __syncthreads();
    float e0 = expf(v0 - m) + expf(v1 - m) + ((t < 128) ? expf(v2 - m) : 0.f);
    red[t] = e0;
    if (t < 64) red[t + 192] = 0.f;
    __syncthreads();
    for (int s2 = 128; s2 > 0; s2 >>= 1) {
        if (t < s2) red[t] += red[t + s2];
        __syncthreads();
    }
    float inv = 1.0f / red[0];
    if (t < 64) {
        int gs = b * SS + s0 + t;
        al[t]  = expf(sc[s0 + t] - m) * inv;
        lsf[t] = (subj_pos[gs] == PPOS);
        lof[t] = (obj_pos[gs] == PPOS);
    }
    __syncthreads();
    // --- pool + masked maxes over this 64-row chunk ---
    const float4* in4 = (const float4*)inputs;
    float4 pool = make_float4(0.f, 0.f, 0.f, 0.f);
    float4 smax = make_float4(NINF, NINF, NINF, NINF);
    float4 omax = make_float4(NINF, NINF, NINF, NINF);
    for (int s = 0; s < 64; ++s) {
        float4 x = in4[((size_t)(b * SS + s0 + s)) * 192 + t];
        float a = al[s];
        pool.x += a * x.x; pool.y += a * x.y; pool.z += a * x.z; pool.w += a * x.w;
        if (lsf[s]) {
            smax.x = fmaxf(smax.x, x.x); smax.y = fmaxf(smax.y, x.y);
            smax.z = fmaxf(smax.z, x.z); smax.w = fmaxf(smax.w, x.w);
        }
        if (lof[s]) {
            omax.x = fmaxf(omax.x, x.x); omax.y = fmaxf(omax.y, x.y);
            omax.z = fmaxf(omax.z, x.z); omax.w = fmaxf(omax.w, x.w);
        }
    }
    size_t o = (size_t)(b * 8 + chunk) * 192 + t;
    ((float4*)(ws + OFF_PP))[o] = pool;
    ((float4*)(ws + OFF_PS))[o] = smax;
    ((float4*)(ws + OFF_PO))[o] = omax;
}

// K5: reduce 8 chunk partials -> pooled, and subj/obj maxes directly into CAT
__global__ void k_reduce(float* __restrict__ ws) {
    int i = blockIdx.x * 256 + threadIdx.x;   // 0..98303
    int b = i / HH, h = i - b * HH;
    float p = 0.f, sm = NINF, om = NINF;
    #pragma unroll
    for (int j = 0; j < 8; ++j) {
        int o = (b * 8 + j) * HH + h;
        p += ws[OFF_PP + o];
        sm = fmaxf(sm, ws[OFF_PS + o]);
        om = fmaxf(om, ws[OFF_PO + o]);
    }
    ws[OFF_POOLED + i] = p;
    ws[OFF_CAT + (size_t)b * 2304 + h] = sm;
    ws[OFF_CAT + (size_t)b * 2304 + 768 + h] = om;
}

// K8: layernorm -> ctx output (d_out offset 5376) AND cat[:, 1536:2304]
__global__ void k_ln(const float* __restrict__ ln_g, const float* __restrict__ ln_b,
                     float* __restrict__ ws, float* __restrict__ out) {
    __shared__ float red[256];
    __shared__ float red2[256];
    int b = blockIdx.x, t = threadIdx.x;
    const float* x = ws + OFF_CTXB + (size_t)b * HH;
    float a0 = x[t], a1 = x[t + 256], a2 = x[t + 512];
    red[t]  = a0 + a1 + a2;
    red2[t] = a0 * a0 + a1 * a1 + a2 * a2;
    __syncthreads();
    for (int s2 = 128; s2 > 0; s2 >>= 1) {
        if (t < s2) { red[t] += red[t + s2]; red2[t] += red2[t + s2]; }
        __syncthreads();
    }
    float mu  = red[0] * (1.0f / 768.0f);
    float var = red2[0] * (1.0f / 768.0f) - mu * mu;
    float inv = rsqrtf(var + 1e-5f);
    float* o = out + 5376 + (size_t)b * HH;
    float* cc = ws + OFF_CAT + (size_t)b * 2304 + 1536;
    float r0 = (a0 - mu) * inv * ln_g[t]       + ln_b[t];
    float r1 = (a1 - mu) * inv * ln_g[t + 256] + ln_b[t + 256];
    float r2 = (a2 - mu) * inv * ln_g[t + 512] + ln_b[t + 512];
    o[t] = r0; o[t + 256] = r1; o[t + 512] = r2;
    cc[t] = r0; cc[t + 256] = r1; cc[t + 512] = r2;
}

extern "C" void kernel_launch(void* const* d_in, const int* in_sizes, int n_in,
                              void* d_out, int out_size, void* d_ws, size_t ws_size,
                              hipStream_t stream) {
    const float* inputs    = (const float*)d_in[0];
    const int*   pos_ids   = (const int*)d_in[1];
    const int*   subj_pos  = (const int*)d_in[3];
    const int*   obj_pos   = (const int*)d_in[4];
    const float* WQ        = (const float*)d_in[6];
    const float* bQ        = (const float*)d_in[7];
    const float* WK        = (const float*)d_in[8];
    const float* bK        = (const float*)d_in[9];
    const float* WV_w      = (const float*)d_in[10];
    const float* WV_b      = (const float*)d_in[11];
    const float* Wout_w    = (const float*)d_in[12];
    const float* Wout_b    = (const float*)d_in[13];
    const float* ln_g      = (const float*)d_in[14];
    const float* ln_b      = (const float*)d_in[15];
    const float* label_emb = (const float*)d_in[16];
    const float* feat_w    = (const float*)d_in[17];
    const float* feat_b    = (const float*)d_in[18];
    const float* out_w     = (const float*)d_in[19];
    const float* out_b     = (const float*)d_in[20];
    float* out = (float*)d_out;
    float* ws  = (float*)d_ws;

    k_kvec2  <<<656, 256, 0, stream>>>(label_emb, WK, bK, ws);
    k_weff2  <<<124, 256, 0, stream>>>(WQ, bQ, ws);
    k_scores <<<2048, 256, 0, stream>>>(inputs, pos_ids, subj_pos, obj_pos, ws);
    k_pool   <<<dim3(8, BB), 192, 0, stream>>>(inputs, subj_pos, obj_pos, ws);
    k_reduce <<<384, 256, 0, stream>>>(ws);
    // ctx_a = pooled @ WV_w.T + WV_b          (M=128,N=768,K=768)
    k_mm<192,0,2><<<768, 256, 0, stream>>>(ws + OFF_POOLED, WV_w, WV_b, ws + OFF_CTXA, BB, HH);
    // ctx_b = gelu(ctx_a @ Wout_w.T + Wout_b) (M=128,N=768,K=768)
    k_mm<192,1,2><<<768, 256, 0, stream>>>(ws + OFF_CTXA, Wout_w, Wout_b, ws + OFF_CTXB, BB, HH);
    k_ln     <<<BB, 256, 0, stream>>>(ln_g, ln_b, ws, out);
    // feats1 = gelu(cat @ feat_w.T + feat_b)  (M=128,N=768,K=2304)
    k_mm<576,1,2><<<768, 256, 0, stream>>>(ws + OFF_CAT, feat_w, feat_b, ws + OFF_F1, BB, HH);
    // feats2 = gelu(f1 @ out_w.T + out_b)     (M=128,N=300,K=768)
    k_mm<192,1,2><<<304, 256, 0, stream>>>(ws + OFF_F1, out_w, out_b, ws + OFF_F2, BB, 300);
    // logits = f2 @ label_emb.T               (M=128,N=42,K=300)
    k_mm<75,0,2><<<48, 256, 0, stream>>>(ws + OFF_F2, label_emb, nullptr, out, BB, 42);
}